// Round 1
// baseline (209.423 us; speedup 1.0000x reference)
//
#include <hip/hip_runtime.h>

#define HH 256
#define NPIX (HH * HH)
#define TOPK 200
#define MIN_COUNT 400
#define FOCAL 221.0f

__device__ __forceinline__ float waveReduceSumF(float v) {
    #pragma unroll
    for (int off = 32; off > 0; off >>= 1)
        v += __shfl_xor(v, off, 64);
    return v;
}

// One block (256 threads = 4 waves) per batch image.
__global__ __launch_bounds__(256, 2)
void mask2cube_kernel(const float* __restrict__ x, float* __restrict__ out) {
    const int b    = blockIdx.x;
    const int t    = threadIdx.x;
    const int wave = t >> 6;
    const int lane = t & 63;
    const float* __restrict__ xb = x + (size_t)b * NPIX;

    // LDS
    __shared__ float colPartW[4][HH];   // per-wave column weight partials
    __shared__ int   colPartC[4][HH];   // per-wave column count partials
    __shared__ float rowW[HH];          // per-row weight sums (later: prefix)
    __shared__ int   rowC[HH];          // per-row counts     (later: prefix)
    __shared__ float rowWC[HH];         // rowW * ycoord      (later: prefix)
    __shared__ float colW[HH];          // column totals      (later: prefix)
    __shared__ int   colC[HH];
    __shared__ float colWC[HH];
    __shared__ float bN[4], bD[4];      // full-side numerator/denominator
    __shared__ int   bCoord[4], bR[4];  // boundary coord, needed count
    __shared__ float partF[4];
    __shared__ int   partI[4];

    // ---------- Phase 1: stream image, build histograms ----------
    // pixel p = 4*(i*256 + t) + j  ->  row = 4*i + wave, col = 4*lane + j
    float cW0 = 0.f, cW1 = 0.f, cW2 = 0.f, cW3 = 0.f;
    int   cC0 = 0,   cC1 = 0,   cC2 = 0,   cC3 = 0;
    const float4* __restrict__ xv = (const float4*)xb;

    #pragma unroll 4
    for (int i = 0; i < 64; ++i) {
        float4 v = xv[i * 256 + t];
        bool m0 = v.x > 0.5f, m1 = v.y > 0.5f, m2 = v.z > 0.5f, m3 = v.w > 0.5f;
        float w0 = m0 ? v.x : 0.f, w1 = m1 ? v.y : 0.f;
        float w2 = m2 ? v.z : 0.f, w3 = m3 ? v.w : 0.f;
        cW0 += w0; cW1 += w1; cW2 += w2; cW3 += w3;
        cC0 += m0; cC1 += m1; cC2 += m2; cC3 += m3;

        // row sum across this wave (wave covers exactly row 4*i+wave)
        float s  = (w0 + w1) + (w2 + w3);
        float sr = waveReduceSumF(s);
        int cnt = __popcll(__ballot(m0)) + __popcll(__ballot(m1))
                + __popcll(__ballot(m2)) + __popcll(__ballot(m3));
        if (lane == 0) {
            int row = i * 4 + wave;
            rowW[row] = sr;
            rowC[row] = cnt;
        }
    }

    // write column partials (col = 4*lane+j, partial set = wave)
    {
        float4* dstW = (float4*)&colPartW[wave][4 * lane];
        dstW[0] = make_float4(cW0, cW1, cW2, cW3);
        int4* dstC = (int4*)&colPartC[wave][4 * lane];
        dstC[0] = make_int4(cC0, cC1, cC2, cC3);
    }
    __syncthreads();

    // combine partials; thread t owns column t / row t
    {
        float w = colPartW[0][t] + colPartW[1][t] + colPartW[2][t] + colPartW[3][t];
        int   c = colPartC[0][t] + colPartC[1][t] + colPartC[2][t] + colPartC[3][t];
        colW[t]  = w;
        colC[t]  = c;
        colWC[t] = w * (float)t;
        rowWC[t] = rowW[t] * (float)t;
    }
    __syncthreads();

    // ---------- Phase 2: inclusive prefix scans over the 256 bins ----------
    #pragma unroll 1
    for (int s = 1; s < HH; s <<= 1) {
        int   cc = 0, rc = 0;
        float cw = 0.f, cwc = 0.f, rw = 0.f, rwc = 0.f;
        if (t >= s) {
            cc  = colC[t - s];  cw  = colW[t - s];  cwc = colWC[t - s];
            rc  = rowC[t - s];  rw  = rowW[t - s];  rwc = rowWC[t - s];
        }
        __syncthreads();
        if (t >= s) {
            colC[t] += cc;  colW[t] += cw;  colWC[t] += cwc;
            rowC[t] += rc;  rowW[t] += rw;  rowWC[t] += rwc;
        }
        __syncthreads();
    }

    const int   totalC = colC[HH - 1];
    const float totW   = colW[HH - 1];
    const float totWC  = colWC[HH - 1];
    const float totWCr = rowWC[HH - 1];

    if (totalC <= MIN_COUNT) {   // invalid row -> zeros (uniform branch)
        if (t < 7) out[b * 7 + t] = 0.f;
        return;
    }

    // ---------- Phase 3: boundary detection ----------
    {
        int   Pc   = colC[t];
        int   Pcm1 = t ? colC[t - 1] : 0;
        float wP   = colW[t],  wcP   = colWC[t];
        float wPm1 = t ? colW[t - 1]  : 0.f;
        float wcPm1= t ? colWC[t - 1] : 0.f;
        // x_min (k=1): smallest columns first
        if (Pcm1 < TOPK && Pc >= TOPK) {
            bCoord[1] = t; bR[1] = TOPK - Pcm1; bN[1] = wcPm1; bD[1] = wPm1;
        }
        // x_max (k=0): largest columns first
        if ((totalC - Pc) < TOPK && (totalC - Pcm1) >= TOPK) {
            bCoord[0] = t; bR[0] = TOPK - (totalC - Pc);
            bN[0] = totWC - wcP; bD[0] = totW - wP;
        }
        int   Rc   = rowC[t];
        int   Rcm1 = t ? rowC[t - 1] : 0;
        float rwP  = rowW[t],  rwcP  = rowWC[t];
        float rwPm1 = t ? rowW[t - 1]  : 0.f;
        float rwcPm1= t ? rowWC[t - 1] : 0.f;
        // y_min (k=3): smallest rows first
        if (Rcm1 < TOPK && Rc >= TOPK) {
            bCoord[3] = t; bR[3] = TOPK - Rcm1; bN[3] = rwcPm1; bD[3] = rwPm1;
        }
        // y_max (k=2): largest rows first
        if ((totalC - Rc) < TOPK && (totalC - Rcm1) >= TOPK) {
            bCoord[2] = t; bR[2] = TOPK - (totalC - Rc);
            bN[2] = totWCr - rwcP; bD[2] = totW - rwP;
        }
    }
    __syncthreads();

    // ---------- Phase 4: boundary-line partial sums (exact tie-break) ----------
    float means[4];
    #pragma unroll
    for (int k = 0; k < 4; ++k) {
        const int cs = bCoord[k];
        const int r  = bR[k];
        // k<2: boundary is column cs, scan order = increasing y (= flat index)
        // k>=2: boundary is row cs,   scan order = increasing x (= flat index)
        float w = (k < 2) ? xb[(size_t)t * HH + cs]
                          : xb[(size_t)cs * HH + t];
        bool m = w > 0.5f;
        unsigned long long bal = __ballot(m);
        int lanePfx = __popcll(bal & ((1ull << lane) - 1ull));
        int wTot    = __popcll(bal);
        if (lane == 0) partI[wave] = wTot;
        __syncthreads();
        int wOff = 0;
        #pragma unroll
        for (int ww = 0; ww < 4; ++ww)
            if (ww < wave) wOff += partI[ww];
        int pfx = wOff + lanePfx;
        float sel = (m && (pfx < r)) ? w : 0.f;
        float sr = waveReduceSumF(sel);
        if (lane == 0) partF[wave] = sr;
        __syncthreads();
        float part = (partF[0] + partF[1]) + (partF[2] + partF[3]);
        float N = bN[k] + part * (float)cs;
        float D = bD[k] + part;
        means[k] = N / D;
        __syncthreads();
    }

    // ---------- Phase 5: final 7-vector ----------
    if (t == 0) {
        float x_maxw = means[0], x_minw = means[1];
        float y_maxw = means[2], y_minw = means[3];
        float y_min = 255.0f - y_maxw;
        float y_max = 255.0f - y_minw;
        float z = 1.0f + y_min / 128.0f;
        float xm = x_minw - 128.0f;
        float xM = x_maxw - 128.0f;
        float x3min = xm / FOCAL / z;
        float x3max = xM / FOCAL / z;
        float y3min = y_min / FOCAL / z;
        float y3max = y_max / FOCAL / z;
        float* o = out + b * 7;
        o[0] = (x3max + x3min) * 0.5f;
        o[1] = (y3max + y3min) * 0.5f;
        o[2] = z;
        o[3] = (x3max - x3min) * 0.5f;
        o[4] = (y3max - y3min) * 0.5f;
        o[5] = 0.1f;
        o[6] = 0.0f;
    }
}

extern "C" void kernel_launch(void* const* d_in, const int* in_sizes, int n_in,
                              void* d_out, int out_size, void* d_ws, size_t ws_size,
                              hipStream_t stream) {
    const float* x = (const float*)d_in[0];
    float* out = (float*)d_out;
    const int B = in_sizes[0] / NPIX;
    mask2cube_kernel<<<B, 256, 0, stream>>>(x, out);
}